// Round 4
// baseline (1785.077 us; speedup 1.0000x reference)
//
#include <hip/hip_runtime.h>
#include <math.h>

// Problem constants
#define VV   50000
#define CC0  2000
#define CC1  10000
#define ED   512
#define HD   1024
#define BBATCH 32
#define TT   128
#define HH1  256
#define HH2  64
#define SS1  8000
#define SS2  40000
#define NR   4064        // B*(T-1) = 32*127
#define G3   3072        // 3*H

// Workspace layout (offsets in floats).
// Aliases (time-disjoint):
//   embA (bf16 4064x512)  @ OFF_YSB  -- dead once xp GEMM done; ysb written by GRU later
//   wihb (bf16 3072x512)  @ OFF_WIHB -- scratch, only used by xp GEMM
//   t2b  (bf16 40000x64)  @ OFF_XP   -- converted after GRU (xp dead), used by tail2
//   hb2  (bf16 32x1024)   @ OFF_P1B  -- third GRU h-buffer; p1b written only after GRU
#define OFF_XP   0ull                      // xp fp32: 12,484,608
#define OFF_YSB  12484608ull               // ys bf16: 4,161,536 u16 = 2,080,768 fl
#define OFF_HB   14565376ull               // hb0+hb1: 65,536 u16 = 32,768 fl
#define OFF_HT   14598144ull               // hT fp32: 32,768
#define OFF_P1B  14630912ull               // proj1 bf16: 520,192 fl (hb2 aliases first 16,384 fl)
#define OFF_P2B  15151104ull               // proj2 bf16: 130,048 fl
#define OFF_WHB  15281152ull               // head_w bf16: 1,025,024 fl
#define OFF_T1B  16306176ull               // t1 bf16: 1,024,000 fl
#define OFF_PP1  17330176ull               // p1 bf16: 131,072 fl
#define OFF_PP2  17461248ull               // p2 bf16: 32,768 fl
#define OFF_SUM  17494016ull               // 6*4064 floats
#define OFF_LOSS (OFF_SUM + 6ull*4064ull)  // 64 floats
#define OFF_INT  (OFF_LOSS + 64ull)        // ints: targets,hselc,list1,list2,cnt,flags
#define OFF_WIHB (OFF_INT + 8ull*4064ull)  // w_ih bf16 scratch: 786,432 fl

#define ZERO_N (6*4064 + 64)
#define NBG 64            // GRU grid

typedef __attribute__((ext_vector_type(8))) __bf16 bf16x8;
typedef __attribute__((ext_vector_type(4))) float f32x4;
typedef __attribute__((ext_vector_type(4))) unsigned int u32x4;
typedef unsigned long long u64;
typedef unsigned short u16;
struct ull2s { u64 x, y; };

__device__ __forceinline__ u16 f2bf(float f) {
    unsigned u = __builtin_bit_cast(unsigned, f);
    u += 0x7fff + ((u >> 16) & 1);          // round-to-nearest-even
    return (u16)(u >> 16);
}

// ---------------------------------------------------------------------------
// init: h0 -> bf16 buffer, zero the sum/loss region, counters, flag lines
__global__ void init_k(const float* __restrict__ hidden, u16* __restrict__ hb0,
                       float* __restrict__ zreg, int* __restrict__ cnt1,
                       int* __restrict__ cnt2, int* __restrict__ bar)
{
    int i = blockIdx.x * 256 + threadIdx.x;
    if (i < BBATCH * HD) hb0[i] = f2bf(hidden[i]);
    int zi = i - BBATCH * HD;
    if (zi >= 0 && zi < ZERO_N) zreg[zi] = 0.f;
    if (zi == ZERO_N) { *cnt1 = 0; *cnt2 = 0; }
    int bi = zi - (ZERO_N + 1);
    if (bi >= 0 && bi < 2048) bar[bi] = 0;
}

// prep: targets, head sel-cols, cluster row lists
__global__ void prep_k(const int* __restrict__ x, int* __restrict__ targets,
                       int* __restrict__ hselc, int* __restrict__ list1,
                       int* __restrict__ list2, int* __restrict__ cnt1, int* __restrict__ cnt2)
{
    int n = blockIdx.x * 256 + threadIdx.x;
    if (n >= NR) return;
    int b = n / 127, t = n % 127;
    int tgt = x[b * TT + t + 1];
    targets[n] = tgt;
    hselc[n] = (tgt < CC0) ? tgt : ((tgt < CC1) ? CC0 : CC0 + 1);
    if (tgt >= CC0 && tgt < CC1) list1[atomicAdd(cnt1, 1)] = n;
    else if (tgt >= CC1)         list2[atomicAdd(cnt2, 1)] = n;
}

// fp32 -> bf16 convert (n4 float4 groups)
__global__ void cvt_bf16_k(const float* __restrict__ src, u16* __restrict__ dst, int n4)
{
    int i = blockIdx.x * 256 + threadIdx.x;
    if (i >= n4) return;
    float4 f = *(const float4*)(src + 4 * (size_t)i);
    union { u16 h[4]; u64 v; } u;
    u.h[0] = f2bf(f.x); u.h[1] = f2bf(f.y); u.h[2] = f2bf(f.z); u.h[3] = f2bf(f.w);
    *(u64*)&dst[4 * (size_t)i] = u.v;
}

// fused fp32 -> bf16 convert over 5 weight buffers (one launch)
__global__ void cvt_multi_k(const float* __restrict__ s0, u16* __restrict__ d0, int n0,
                            const float* __restrict__ s1, u16* __restrict__ d1, int n1,
                            const float* __restrict__ s2, u16* __restrict__ d2, int n2,
                            const float* __restrict__ s3, u16* __restrict__ d3, int n3,
                            const float* __restrict__ s4, u16* __restrict__ d4, int n4)
{
    int i = blockIdx.x * 256 + threadIdx.x;
    const float* s; u16* d; int off = i;
    if (off < n0) { s = s0; d = d0; }
    else if ((off -= n0) < n1) { s = s1; d = d1; }
    else if ((off -= n1) < n2) { s = s2; d = d2; }
    else if ((off -= n2) < n3) { s = s3; d = d3; }
    else if ((off -= n3) < n4) { s = s4; d = d4; }
    else return;
    float4 f = *(const float4*)(s + 4 * (size_t)off);
    union { u16 h[4]; u64 v; } u;
    u.h[0] = f2bf(f.x); u.h[1] = f2bf(f.y); u.h[2] = f2bf(f.z); u.h[3] = f2bf(f.w);
    *(u64*)&d[4 * (size_t)off] = u.v;
}

// gather used embedding rows -> compact bf16 A matrix, row n = t*32+b (xp order)
__global__ void emb_gather_k(const int* __restrict__ x, const float* __restrict__ emb,
                             u16* __restrict__ embA)
{
    int idx = blockIdx.x * 256 + threadIdx.x;   // NR*64 threads, 8 floats each
    if (idx >= NR * 64) return;
    int n = idx >> 6;
    int kk = (idx & 63) << 3;
    int b = n & 31, t = n >> 5;
    int tok = x[b * TT + t];
    const float* ap = emb + (size_t)tok * ED + kk;
    float4 f0 = *(const float4*)ap;
    float4 f1 = *(const float4*)(ap + 4);
    union { u16 h[8]; u32x4 v; } u;
    u.h[0] = f2bf(f0.x); u.h[1] = f2bf(f0.y); u.h[2] = f2bf(f0.z); u.h[3] = f2bf(f0.w);
    u.h[4] = f2bf(f1.x); u.h[5] = f2bf(f1.y); u.h[6] = f2bf(f1.z); u.h[7] = f2bf(f1.w);
    *(u32x4*)&embA[(size_t)n * ED + kk] = u.v;
}

// ---------------------------------------------------------------------------
// bf16 MFMA GEMM, 128x128 tile, BK=32, 4 waves (2x2 of 64x64).
// A: bf16 rows (direct n or via rowmap/cnt). B: bf16 (or fp32 if BFP32) rows=cols.
// EPI 0: store C bf16 to outB. EPI 1: head exp-sum (selcol). EPI 2: tail exp-sum.
// EPI 3: store C fp32 to gsum with bias add from gsel (ldo = row stride).
// MFMA layouts (HW-verified in GRU): A[m=lane&15][k=quad*8+j],
// B[n=lane&15][k=quad*8+j], C row=quad*4+reg, col=lane&15.
template<int EPI, int BFP32>
__global__ void __launch_bounds__(256)
mfma_gemm_k(const u16* __restrict__ Ab, const void* __restrict__ Bsrc,
            int Mdirect, int N, int K,
            const int* __restrict__ rowmap, const int* __restrict__ cntp,
            u16* __restrict__ outB, int ldo,
            float* __restrict__ gsum, float* __restrict__ gsel,
            const int* __restrict__ selcol, const int* __restrict__ targets, int lo)
{
    const int M = cntp ? *cntp : Mdirect;
    const int rbase = blockIdx.x * 128;
    if (rbase >= M) return;
    const int cbase = blockIdx.y * 128;

    __shared__ u16 As[128 * 40];
    __shared__ u16 Bs[128 * 40];
    __shared__ const u16* aptr[128];
    __shared__ int rown[128];
    __shared__ float redl[128 * 2];

    const int tid = threadIdx.x;
    if (tid < 128) {
        int rid = -1;
        if (rbase + tid < M) rid = rowmap ? rowmap[rbase + tid] : (rbase + tid);
        rown[tid] = rid;
        aptr[tid] = (rid >= 0) ? (Ab + (size_t)rid * K) : nullptr;
    }
    __syncthreads();

    const int lane = tid & 63, wid = tid >> 6;
    const int n16 = lane & 15, quad = lane >> 4;
    const int m0 = (wid >> 1) * 64, n0 = (wid & 1) * 64;
    const int i = tid >> 1, half = tid & 1;

    f32x4 acc[4][4];
#pragma unroll
    for (int a = 0; a < 4; a++)
#pragma unroll
        for (int b = 0; b < 4; b++) acc[a][b] = (f32x4){0.f, 0.f, 0.f, 0.f};

    for (int k0 = 0; k0 < K; k0 += 32) {
        // fetch A (bf16)
        const u16* ap = aptr[i];
        u32x4 a0 = {0,0,0,0}, a1 = a0;
        if (ap) {
            a0 = *(const u32x4*)(ap + k0 + half * 16);
            a1 = *(const u32x4*)(ap + k0 + half * 16 + 8);
        }
        // fetch B
        u32x4 b0 = {0,0,0,0}, b1 = b0;
        int c = cbase + i;
        if (c < N) {
            if (BFP32) {
                const float* bp = (const float*)Bsrc + (size_t)c * K + k0 + half * 16;
                float4 f0 = *(const float4*)(bp);
                float4 f1 = *(const float4*)(bp + 4);
                float4 f2 = *(const float4*)(bp + 8);
                float4 f3 = *(const float4*)(bp + 12);
                union { u16 h[16]; u32x4 v[2]; } u;
                u.h[0]=f2bf(f0.x); u.h[1]=f2bf(f0.y); u.h[2]=f2bf(f0.z); u.h[3]=f2bf(f0.w);
                u.h[4]=f2bf(f1.x); u.h[5]=f2bf(f1.y); u.h[6]=f2bf(f1.z); u.h[7]=f2bf(f1.w);
                u.h[8]=f2bf(f2.x); u.h[9]=f2bf(f2.y); u.h[10]=f2bf(f2.z); u.h[11]=f2bf(f2.w);
                u.h[12]=f2bf(f3.x); u.h[13]=f2bf(f3.y); u.h[14]=f2bf(f3.z); u.h[15]=f2bf(f3.w);
                b0 = u.v[0]; b1 = u.v[1];
            } else {
                const u16* bp = (const u16*)Bsrc + (size_t)c * K + k0 + half * 16;
                b0 = *(const u32x4*)(bp);
                b1 = *(const u32x4*)(bp + 8);
            }
        }
        __syncthreads();                    // previous compute done before overwrite
        *(u32x4*)&As[i * 40 + half * 16]     = a0;
        *(u32x4*)&As[i * 40 + half * 16 + 8] = a1;
        *(u32x4*)&Bs[i * 40 + half * 16]     = b0;
        *(u32x4*)&Bs[i * 40 + half * 16 + 8] = b1;
        __syncthreads();

        bf16x8 av[4], bv[4];
#pragma unroll
        for (int mi = 0; mi < 4; mi++)
            av[mi] = *(const bf16x8*)&As[(m0 + mi * 16 + n16) * 40 + quad * 8];
#pragma unroll
        for (int ni = 0; ni < 4; ni++)
            bv[ni] = *(const bf16x8*)&Bs[(n0 + ni * 16 + n16) * 40 + quad * 8];
#pragma unroll
        for (int mi = 0; mi < 4; mi++)
#pragma unroll
            for (int ni = 0; ni < 4; ni++)
                acc[mi][ni] = __builtin_amdgcn_mfma_f32_16x16x32_bf16(
                    av[mi], bv[ni], acc[mi][ni], 0, 0, 0);
    }

    __syncthreads();
    if (EPI == 0) {
#pragma unroll
        for (int mi = 0; mi < 4; mi++)
#pragma unroll
            for (int ni = 0; ni < 4; ni++)
#pragma unroll
                for (int r = 0; r < 4; r++) {
                    int row = rbase + m0 + mi * 16 + quad * 4 + r;
                    int col = cbase + n0 + ni * 16 + n16;
                    if (row < M && col < N)
                        outB[(size_t)row * ldo + col] = f2bf(acc[mi][ni][r]);
                }
    } else if (EPI == 3) {
        // fp32 out + bias: gsum = out matrix [M x ldo], gsel = bias[N]
#pragma unroll
        for (int mi = 0; mi < 4; mi++)
#pragma unroll
            for (int ni = 0; ni < 4; ni++)
#pragma unroll
                for (int r = 0; r < 4; r++) {
                    int row = rbase + m0 + mi * 16 + quad * 4 + r;
                    int col = cbase + n0 + ni * 16 + n16;
                    if (row < M && col < N)
                        gsum[(size_t)row * ldo + col] = acc[mi][ni][r] + gsel[col];
                }
    } else {
#pragma unroll
        for (int mi = 0; mi < 4; mi++)
#pragma unroll
            for (int r = 0; r < 4; r++) {
                int lrow = m0 + mi * 16 + quad * 4 + r;
                int nid = rown[lrow];
                float s = 0.f;
                if (nid >= 0) {
                    int sc = (EPI == 1) ? selcol[nid] : (targets[nid] - lo);
#pragma unroll
                    for (int ni = 0; ni < 4; ni++) {
                        int col = cbase + n0 + ni * 16 + n16;
                        if (col < N) {
                            float v = acc[mi][ni][r];
                            s += __expf(v);
                            if (col == sc) gsel[nid] = v;
                        }
                    }
                }
                s += __shfl_xor(s, 1);
                s += __shfl_xor(s, 2);
                s += __shfl_xor(s, 4);
                s += __shfl_xor(s, 8);
                if (n16 == 0) redl[lrow * 2 + (wid & 1)] = s;
            }
        __syncthreads();
        if (tid < 128) {
            int nid = rown[tid];
            if (nid >= 0) atomicAdd(&gsum[nid], redl[tid * 2] + redl[tid * 2 + 1]);
        }
    }
}

// ---------------------------------------------------------------------------
// Persistent MFMA GRU: 64 blocks x 128 threads, NO global barrier.
// Per-producer flags (own LLC line each, stride-32 ints): flag[c]=t+1 once
// block c's h chunk for step t is stored+drained. Consumers gather all 64
// flags in ONE parallel vector load (64 lanes -> 64 lines), ballot which
// 32-col k-chunks are ready, and consume them progressively (loads batched
// before MFMAs so latencies pipeline), re-polling for stragglers. Straggler
// wait overlaps the bulk of the h-gather + MFMA work.
// Write-after-read safety: 3 rotating h buffers (read t%3, write (t+1)%3).
// A block writes buf[(t+1)%3] only after observing all flags >= t, which
// implies every block finished reads of steps t-1 and t-2; the previous
// reader of buf[(t+1)%3] was step t-2. ys written bf16 (row = b*127 + t).
__global__ void __launch_bounds__(128, 1)
gru_persist_k(const float* __restrict__ xp, const float* __restrict__ hidden,
              u16* __restrict__ hb0, u16* __restrict__ hb1, u16* __restrict__ hb2,
              const float* __restrict__ w_hh, const float* __restrict__ b_hh,
              const int* __restrict__ lengths, u16* __restrict__ ys,
              float* __restrict__ hT, int* __restrict__ flags)
{
    __shared__ u16 Blds[48 * 1032];          // 97 KB, row = g*16+c, +8 pad
    const int tid = threadIdx.x;
    const int bid = blockIdx.x;
    const int j0 = bid * 16;
    const int lane = tid & 63, wid = tid >> 6;
    const int n16 = lane & 15, quad = lane >> 4;

    for (int idx = tid; idx < 48 * 1024; idx += 128) {
        int r = idx >> 10, k = idx & 1023;
        int g = r >> 4, c = r & 15;
        Blds[r * 1032 + k] = f2bf(w_hh[(size_t)(g * HD + j0 + c) * HD + k]);
    }

    const int col = j0 + n16;
    float bh0 = b_hh[col], bh1 = b_hh[HD + col], bh2 = b_hh[2 * HD + col];
    float hold[4];
    int len[4];
#pragma unroll
    for (int r = 0; r < 4; r++) {
        int b = wid * 16 + quad * 4 + r;
        len[r] = lengths[b];
        hold[r] = hidden[b * HD + col];
    }
    __syncthreads();

    // prefetch xp for t = 0
    float xrv[4], xzv[4], xnv[4];
#pragma unroll
    for (int r = 0; r < 4; r++) {
        int b = wid * 16 + quad * 4 + r;
        const float* xpt = xp + (size_t)b * G3 + col;
        xrv[r] = xpt[0]; xzv[r] = xpt[HD]; xnv[r] = xpt[2 * HD];
    }

    const int boff = n16 * 1032 + quad * 8;
    const size_t rowoff = (size_t)(wid * 16 + n16) * HD + quad * 8;

    for (int t = 0; t < TT - 1; t++) {
        int m3 = t % 3;
        const u16* hbR = (m3 == 0) ? hb0 : ((m3 == 1) ? hb1 : hb2);
        int w3 = (t + 1) % 3;
        u16* hbW = (w3 == 0) ? hb0 : ((w3 == 1) ? hb1 : hb2);

        f32x4 acc0 = {0.f, 0.f, 0.f, 0.f}, acc1 = acc0, acc2 = acc0;

        // ---- progressive chunk consumption ----
        unsigned rem = 0xFFFFFFFFu;
        int spin = 0;
        while (rem) {
            int f = __hip_atomic_load(&flags[lane * 32], __ATOMIC_RELAXED,
                                      __HIP_MEMORY_SCOPE_AGENT);
            u64 m = __ballot(f >= t);
            u64 q = m & (m >> 1);                 // bit 2ks: both producers ready
            unsigned ready = 0;
#pragma unroll
            for (int ks = 0; ks < 32; ks++)
                ready |= (unsigned)((q >> (2 * ks)) & 1ull) << ks;
            unsigned todo = ready & rem;
            if (!todo) {
                if (++spin < (1 << 18)) { __builtin_amdgcn_s_sleep(2); continue; }
                todo = rem;                        // bail-out: avoid hang
            }
            todo = __builtin_amdgcn_readfirstlane(todo);   // force uniform branches
            {
                u64 a0buf[32], a1buf[32];
                // pass 1: issue all ready-chunk loads (pipelined latencies)
#pragma unroll
                for (int ks = 0; ks < 32; ks++) {
                    if (todo & (1u << ks)) {
                        const u16* ap = hbR + rowoff + ks * 32;
                        a0buf[ks] = __hip_atomic_load((const u64*)ap,
                                        __ATOMIC_RELAXED, __HIP_MEMORY_SCOPE_AGENT);
                        a1buf[ks] = __hip_atomic_load((const u64*)(ap + 4),
                                        __ATOMIC_RELAXED, __HIP_MEMORY_SCOPE_AGENT);
                    }
                }
                // pass 2: MFMAs for ready chunks
#pragma unroll
                for (int ks = 0; ks < 32; ks++) {
                    if (todo & (1u << ks)) {
                        ull2s av2; av2.x = a0buf[ks]; av2.y = a1buf[ks];
                        bf16x8 av = __builtin_bit_cast(bf16x8, av2);
                        bf16x8 b0 = *(const bf16x8*)&Blds[boff + ks * 32];
                        bf16x8 b1 = *(const bf16x8*)&Blds[16 * 1032 + boff + ks * 32];
                        bf16x8 b2 = *(const bf16x8*)&Blds[32 * 1032 + boff + ks * 32];
                        acc0 = __builtin_amdgcn_mfma_f32_16x16x32_bf16(av, b0, acc0, 0, 0, 0);
                        acc1 = __builtin_amdgcn_mfma_f32_16x16x32_bf16(av, b1, acc1, 0, 0, 0);
                        acc2 = __builtin_amdgcn_mfma_f32_16x16x32_bf16(av, b2, acc2, 0, 0, 0);
                    }
                }
            }
            rem &= ~todo;
        }

        // ---- epilogue: gates + h store ----
        float ysv[4];
#pragma unroll
        for (int r = 0; r < 4; r++) {
            int b = wid * 16 + quad * 4 + r;
            float hr = acc0[r] + bh0, hz = acc1[r] + bh1, hn = acc2[r] + bh2;
            float rg = 1.f / (1.f + __expf(-(xrv[r] + hr)));
            float zg = 1.f / (1.f + __expf(-(xzv[r] + hz)));
            float nv = tanhf(xnv[r] + rg * hn);
            bool valid = t < (len[r] - 1);
            float hnew = valid ? (1.f - zg) * nv + zg * hold[r] : hold[r];
            hold[r] = hnew;
            ysv[r] = valid ? hnew : 0.f;
            __hip_atomic_store(hbW + (size_t)b * HD + col, f2bf(hnew),
                               __ATOMIC_RELAXED, __HIP_MEMORY_SCOPE_AGENT);
        }

        // ---- publish: h stores drained (both waves), then own flag ----
        __builtin_amdgcn_s_waitcnt(0);
        __syncthreads();
        if (tid == 0)
            __hip_atomic_store(&flags[bid * 32], t + 1, __ATOMIC_RELAXED,
                               __HIP_MEMORY_SCOPE_AGENT);

        // ---- deferred (overlaps other blocks' publishes): ys/hT + xp prefetch ----
#pragma unroll
        for (int r = 0; r < 4; r++) {
            int b = wid * 16 + quad * 4 + r;
            ys[((size_t)b * 127 + t) * HD + col] = f2bf(ysv[r]);
            if (t == TT - 2) hT[b * HD + col] = hold[r];
        }
        const int tn = (t < TT - 2) ? t + 1 : t;   // clamped prefetch
#pragma unroll
        for (int r = 0; r < 4; r++) {
            int b = wid * 16 + quad * 4 + r;
            const float* xpt = xp + ((size_t)tn * BBATCH + b) * G3 + col;
            xrv[r] = xpt[0]; xzv[r] = xpt[HD]; xnv[r] = xpt[2 * HD];
        }
    }
}

// ---------------------------------------------------------------------------
__global__ void finish_k(const float* __restrict__ hsum, const float* __restrict__ hsel,
                         const float* __restrict__ t1sum, const float* __restrict__ t1sel,
                         const float* __restrict__ t2sum, const float* __restrict__ t2sel,
                         const int* __restrict__ targets, float* __restrict__ losssum)
{
    __shared__ float red[256];
    int n = blockIdx.x * 256 + threadIdx.x;
    float lp = 0.f;
    if (n < NR) {
        lp = hsel[n] - logf(hsum[n]);
        int tgt = targets[n];
        if (tgt >= CC1)      lp += t2sel[n] - logf(t2sum[n]);
        else if (tgt >= CC0) lp += t1sel[n] - logf(t1sum[n]);
    }
    red[threadIdx.x] = lp;
    __syncthreads();
    for (int s = 128; s > 0; s >>= 1) {
        if (threadIdx.x < s) red[threadIdx.x] += red[threadIdx.x + s];
        __syncthreads();
    }
    if (threadIdx.x == 0) atomicAdd(losssum, red[0]);
}

__global__ void out_k(const float* __restrict__ losssum, const float* __restrict__ hT,
                      float* __restrict__ out)
{
    int i = blockIdx.x * 256 + threadIdx.x;
    if (i == 0) out[0] = -losssum[0] / (float)NR;
    if (i < BBATCH * HD) out[1 + i] = hT[i];
}

// ---------------------------------------------------------------------------
extern "C" void kernel_launch(void* const* d_in, const int* in_sizes, int n_in,
                              void* d_out, int out_size, void* d_ws, size_t ws_size,
                              hipStream_t stream)
{
    const int*   x       = (const int*)d_in[0];
    const int*   lengths = (const int*)d_in[1];
    const float* hidden  = (const float*)d_in[2];
    const float* emb     = (const float*)d_in[3];
    const float* w_ih    = (const float*)d_in[4];
    const float* w_hh    = (const float*)d_in[5];
    const float* b_ih    = (const float*)d_in[6];
    const float* b_hh    = (const float*)d_in[7];
    const float* head_w  = (const float*)d_in[8];
    const float* p1      = (const float*)d_in[9];
    const float* t1      = (const float*)d_in[10];
    const float* p2      = (const float*)d_in[11];
    const float* t2      = (const float*)d_in[12];

    float* ws = (float*)d_ws;
    float* xp    = ws + OFF_XP;
    u16*   ysb   = (u16*)(ws + OFF_YSB);
    u16*   hb0   = (u16*)(ws + OFF_HB);
    u16*   hb1   = hb0 + BBATCH * HD;
    float* hT    = ws + OFF_HT;
    u16*   p1b   = (u16*)(ws + OFF_P1B);   // proj1 bf16 out
    u16*   p2b   = (u16*)(ws + OFF_P2B);   // proj2 bf16 out
    u16*   whb   = (u16*)(ws + OFF_WHB);   // head_w bf16
    u16*   t1b   = (u16*)(ws + OFF_T1B);   // t1 bf16
    u16*   pp1b  = (u16*)(ws + OFF_PP1);   // p1 bf16
    u16*   pp2b  = (u16*)(ws + OFF_PP2);   // p2 bf16
    float* hsum  = ws + OFF_SUM;
    float* hsel  = hsum + 4064;
    float* t1sum = hsel + 4064;
    float* t1sel = t1sum + 4064;
    float* t2sum = t1sel + 4064;
    float* t2sel = t2sum + 4064;
    float* losss = ws + OFF_LOSS;
    int* ib      = (int*)(ws + OFF_INT);
    int* targets = ib;
    int* hselc   = ib + 4064;
    int* list1   = ib + 2 * 4064;
    int* list2   = ib + 3 * 4064;
    int* cnt1    = ib + 4 * 4064;
    int* cnt2    = cnt1 + 1;
    int* flags   = ib + 5 * 4064;    // 64 flags x 32-int stride (zeroed by init)

    // time-disjoint aliases
    u16* embA = (u16*)(ws + OFF_YSB);  // bf16 A for xp GEMM (dead before GRU writes ys)
    u16* wihb = (u16*)(ws + OFF_WIHB); // bf16 w_ih scratch
    u16* t2b  = (u16*)(ws + OFF_XP);   // bf16 t2 (converted after GRU; xp dead)
    u16* hb2  = (u16*)(ws + OFF_P1B);  // third GRU h-buffer (p1b written after GRU)

    float* out = (float*)d_out;

    init_k<<<232, 256, 0, stream>>>(hidden, hb0, hsum, cnt1, cnt2, flags);
    prep_k<<<16, 256, 0, stream>>>(x, targets, hselc, list1, list2, cnt1, cnt2);

    // all fp32->bf16 weight converts in one launch:
    // w_ih (393216), head_w (512512), t1 (512000), p1 (65536), p2 (16384)
    cvt_multi_k<<<(1499648 + 255) / 256, 256, 0, stream>>>(
        w_ih, wihb, 393216,
        head_w, whb, 512512,
        t1, t1b, 512000,
        p1, pp1b, 65536,
        p2, pp2b, 16384);

    // xp = embed(x) @ w_ih^T + b_ih   [4064 x 3072] fp32, via bf16 MFMA
    emb_gather_k<<<(NR * 64 + 255) / 256, 256, 0, stream>>>(x, emb, embA);
    mfma_gemm_k<3, 0><<<dim3(32, 24), 256, 0, stream>>>(
        embA, wihb, NR, G3, ED, nullptr, nullptr, nullptr, G3,
        xp, (float*)b_ih, nullptr, nullptr, 0);

    // GRU recurrence: persistent MFMA kernel, per-producer flags, 3 h-buffers
    gru_persist_k<<<NBG, 128, 0, stream>>>(xp, hidden, hb0, hb1, hb2, w_hh, b_hh,
                                           lengths, ysb, hT, flags);

    // t2 fp32 -> bf16 once (into now-dead xp region): tail2 B traffic halves
    cvt_bf16_k<<<(640000 + 255) / 256, 256, 0, stream>>>(t2, t2b, 640000);

    // proj1 = ys @ p1^T  -> bf16 [4064 x 256]
    mfma_gemm_k<0, 0><<<dim3(32, 2), 256, 0, stream>>>(
        ysb, pp1b, NR, HH1, HD, nullptr, nullptr, p1b, HH1,
        nullptr, nullptr, nullptr, nullptr, 0);
    // proj2 = ys @ p2^T  -> bf16 [4064 x 64]
    mfma_gemm_k<0, 0><<<dim3(32, 1), 256, 0, stream>>>(
        ysb, pp2b, NR, HH2, HD, nullptr, nullptr, p2b, HH2,
        nullptr, nullptr, nullptr, nullptr, 0);
    // head: exp-sum + selected logit
    mfma_gemm_k<1, 0><<<dim3(32, 16), 256, 0, stream>>>(
        ysb, whb, NR, CC0 + 2, HD, nullptr, nullptr, nullptr, 0,
        hsum, hsel, hselc, nullptr, 0);
    // tail1 over compacted rows
    mfma_gemm_k<2, 0><<<dim3(32, 63), 256, 0, stream>>>(
        p1b, t1b, 0, SS1, HH1, list1, cnt1, nullptr, 0,
        t1sum, t1sel, nullptr, targets, CC0);
    // tail2 over compacted rows, B = pre-converted bf16 t2
    mfma_gemm_k<2, 0><<<dim3(32, 313), 256, 0, stream>>>(
        p2b, t2b, 0, SS2, HH2, list2, cnt2, nullptr, 0,
        t2sum, t2sel, nullptr, targets, CC1);

    finish_k<<<16, 256, 0, stream>>>(hsum, hsel, t1sum, t1sel, t2sum, t2sel,
                                     targets, losss);
    out_k<<<128, 256, 0, stream>>>(losss, hT, out);
}

// Round 5
// 1600.789 us; speedup vs baseline: 1.1151x; 1.1151x over previous
//
#include <hip/hip_runtime.h>
#include <math.h>

// Problem constants
#define VV   50000
#define CC0  2000
#define CC1  10000
#define ED   512
#define HD   1024
#define BBATCH 32
#define TT   128
#define HH1  256
#define HH2  64
#define SS1  8000
#define SS2  40000
#define NR   4064        // B*(T-1) = 32*127
#define G3   3072        // 3*H

// Workspace layout (offsets in floats).
// Aliases (time-disjoint):
//   embA (bf16 4064x512)  @ OFF_YSB  -- dead once xp GEMM done; ysb written by GRU later
//   wihb (bf16 3072x512)  @ OFF_WIHB -- scratch, only used by xp GEMM
//   t2b  (bf16 40000x64)  @ OFF_XP   -- converted after GRU (xp dead), used by tail2
#define OFF_XP   0ull                      // xp fp32: 12,484,608
#define OFF_YSB  12484608ull               // ys bf16: 4,161,536 u16 = 2,080,768 fl
#define OFF_HB   14565376ull               // hb0+hb1: 65,536 u16 = 32,768 fl
#define OFF_HT   14598144ull               // hT fp32: 32,768
#define OFF_P1B  14630912ull               // proj1 bf16: 520,192 fl
#define OFF_P2B  15151104ull               // proj2 bf16: 130,048 fl
#define OFF_WHB  15281152ull               // head_w bf16: 1,025,024 fl
#define OFF_T1B  16306176ull               // t1 bf16: 1,024,000 fl
#define OFF_PP1  17330176ull               // p1 bf16: 131,072 fl
#define OFF_PP2  17461248ull               // p2 bf16: 32,768 fl
#define OFF_SUM  17494016ull               // 6*4064 floats
#define OFF_LOSS (OFF_SUM + 6ull*4064ull)  // 64 floats
#define OFF_INT  (OFF_LOSS + 64ull)        // ints: targets,hselc,list1,list2,cnt,flags
#define OFF_WIHB (OFF_INT + 8ull*4064ull)  // w_ih bf16 scratch: 786,432 fl

#define ZERO_N (6*4064 + 64)
#define NBG 64            // GRU grid

typedef __attribute__((ext_vector_type(8))) __bf16 bf16x8;
typedef __attribute__((ext_vector_type(4))) float f32x4;
typedef __attribute__((ext_vector_type(4))) unsigned int u32x4;
typedef unsigned long long u64;
typedef unsigned short u16;
struct ull2s { u64 x, y; };

__device__ __forceinline__ u16 f2bf(float f) {
    unsigned u = __builtin_bit_cast(unsigned, f);
    u += 0x7fff + ((u >> 16) & 1);          // round-to-nearest-even
    return (u16)(u >> 16);
}

// ---------------------------------------------------------------------------
// init: h0 -> bf16 buffer, zero the sum/loss region, counters, flag lines
__global__ void init_k(const float* __restrict__ hidden, u16* __restrict__ hb0,
                       float* __restrict__ zreg, int* __restrict__ cnt1,
                       int* __restrict__ cnt2, int* __restrict__ bar)
{
    int i = blockIdx.x * 256 + threadIdx.x;
    if (i < BBATCH * HD) hb0[i] = f2bf(hidden[i]);
    int zi = i - BBATCH * HD;
    if (zi >= 0 && zi < ZERO_N) zreg[zi] = 0.f;
    if (zi == ZERO_N) { *cnt1 = 0; *cnt2 = 0; }
    int bi = zi - (ZERO_N + 1);
    if (bi >= 0 && bi < 2048) bar[bi] = 0;
}

// prep: targets, head sel-cols, cluster row lists
__global__ void prep_k(const int* __restrict__ x, int* __restrict__ targets,
                       int* __restrict__ hselc, int* __restrict__ list1,
                       int* __restrict__ list2, int* __restrict__ cnt1, int* __restrict__ cnt2)
{
    int n = blockIdx.x * 256 + threadIdx.x;
    if (n >= NR) return;
    int b = n / 127, t = n % 127;
    int tgt = x[b * TT + t + 1];
    targets[n] = tgt;
    hselc[n] = (tgt < CC0) ? tgt : ((tgt < CC1) ? CC0 : CC0 + 1);
    if (tgt >= CC0 && tgt < CC1) list1[atomicAdd(cnt1, 1)] = n;
    else if (tgt >= CC1)         list2[atomicAdd(cnt2, 1)] = n;
}

// fp32 -> bf16 convert (n4 float4 groups)
__global__ void cvt_bf16_k(const float* __restrict__ src, u16* __restrict__ dst, int n4)
{
    int i = blockIdx.x * 256 + threadIdx.x;
    if (i >= n4) return;
    float4 f = *(const float4*)(src + 4 * (size_t)i);
    union { u16 h[4]; u64 v; } u;
    u.h[0] = f2bf(f.x); u.h[1] = f2bf(f.y); u.h[2] = f2bf(f.z); u.h[3] = f2bf(f.w);
    *(u64*)&dst[4 * (size_t)i] = u.v;
}

// fused fp32 -> bf16 convert over 5 weight buffers (one launch)
__global__ void cvt_multi_k(const float* __restrict__ s0, u16* __restrict__ d0, int n0,
                            const float* __restrict__ s1, u16* __restrict__ d1, int n1,
                            const float* __restrict__ s2, u16* __restrict__ d2, int n2,
                            const float* __restrict__ s3, u16* __restrict__ d3, int n3,
                            const float* __restrict__ s4, u16* __restrict__ d4, int n4)
{
    int i = blockIdx.x * 256 + threadIdx.x;
    const float* s; u16* d; int off = i;
    if (off < n0) { s = s0; d = d0; }
    else if ((off -= n0) < n1) { s = s1; d = d1; }
    else if ((off -= n1) < n2) { s = s2; d = d2; }
    else if ((off -= n2) < n3) { s = s3; d = d3; }
    else if ((off -= n3) < n4) { s = s4; d = d4; }
    else return;
    float4 f = *(const float4*)(s + 4 * (size_t)off);
    union { u16 h[4]; u64 v; } u;
    u.h[0] = f2bf(f.x); u.h[1] = f2bf(f.y); u.h[2] = f2bf(f.z); u.h[3] = f2bf(f.w);
    *(u64*)&d[4 * (size_t)off] = u.v;
}

// gather used embedding rows -> compact bf16 A matrix, row n = t*32+b (xp order)
__global__ void emb_gather_k(const int* __restrict__ x, const float* __restrict__ emb,
                             u16* __restrict__ embA)
{
    int idx = blockIdx.x * 256 + threadIdx.x;   // NR*64 threads, 8 floats each
    if (idx >= NR * 64) return;
    int n = idx >> 6;
    int kk = (idx & 63) << 3;
    int b = n & 31, t = n >> 5;
    int tok = x[b * TT + t];
    const float* ap = emb + (size_t)tok * ED + kk;
    float4 f0 = *(const float4*)ap;
    float4 f1 = *(const float4*)(ap + 4);
    union { u16 h[8]; u32x4 v; } u;
    u.h[0] = f2bf(f0.x); u.h[1] = f2bf(f0.y); u.h[2] = f2bf(f0.z); u.h[3] = f2bf(f0.w);
    u.h[4] = f2bf(f1.x); u.h[5] = f2bf(f1.y); u.h[6] = f2bf(f1.z); u.h[7] = f2bf(f1.w);
    *(u32x4*)&embA[(size_t)n * ED + kk] = u.v;
}

// ---------------------------------------------------------------------------
// bf16 MFMA GEMM, 128x128 tile, BK=32, 4 waves (2x2 of 64x64).
// A: bf16 rows (direct n or via rowmap/cnt). B: bf16 (or fp32 if BFP32) rows=cols.
// EPI 0: store C bf16 to outB. EPI 1: head exp-sum (selcol). EPI 2: tail exp-sum.
// EPI 3: store C fp32 to gsum with bias add from gsel (ldo = row stride).
template<int EPI, int BFP32>
__global__ void __launch_bounds__(256)
mfma_gemm_k(const u16* __restrict__ Ab, const void* __restrict__ Bsrc,
            int Mdirect, int N, int K,
            const int* __restrict__ rowmap, const int* __restrict__ cntp,
            u16* __restrict__ outB, int ldo,
            float* __restrict__ gsum, float* __restrict__ gsel,
            const int* __restrict__ selcol, const int* __restrict__ targets, int lo)
{
    const int M = cntp ? *cntp : Mdirect;
    const int rbase = blockIdx.x * 128;
    if (rbase >= M) return;
    const int cbase = blockIdx.y * 128;

    __shared__ u16 As[128 * 40];
    __shared__ u16 Bs[128 * 40];
    __shared__ const u16* aptr[128];
    __shared__ int rown[128];
    __shared__ float redl[128 * 2];

    const int tid = threadIdx.x;
    if (tid < 128) {
        int rid = -1;
        if (rbase + tid < M) rid = rowmap ? rowmap[rbase + tid] : (rbase + tid);
        rown[tid] = rid;
        aptr[tid] = (rid >= 0) ? (Ab + (size_t)rid * K) : nullptr;
    }
    __syncthreads();

    const int lane = tid & 63, wid = tid >> 6;
    const int n16 = lane & 15, quad = lane >> 4;
    const int m0 = (wid >> 1) * 64, n0 = (wid & 1) * 64;
    const int i = tid >> 1, half = tid & 1;

    f32x4 acc[4][4];
#pragma unroll
    for (int a = 0; a < 4; a++)
#pragma unroll
        for (int b = 0; b < 4; b++) acc[a][b] = (f32x4){0.f, 0.f, 0.f, 0.f};

    for (int k0 = 0; k0 < K; k0 += 32) {
        // fetch A (bf16)
        const u16* ap = aptr[i];
        u32x4 a0 = {0,0,0,0}, a1 = a0;
        if (ap) {
            a0 = *(const u32x4*)(ap + k0 + half * 16);
            a1 = *(const u32x4*)(ap + k0 + half * 16 + 8);
        }
        // fetch B
        u32x4 b0 = {0,0,0,0}, b1 = b0;
        int c = cbase + i;
        if (c < N) {
            if (BFP32) {
                const float* bp = (const float*)Bsrc + (size_t)c * K + k0 + half * 16;
                float4 f0 = *(const float4*)(bp);
                float4 f1 = *(const float4*)(bp + 4);
                float4 f2 = *(const float4*)(bp + 8);
                float4 f3 = *(const float4*)(bp + 12);
                union { u16 h[16]; u32x4 v[2]; } u;
                u.h[0]=f2bf(f0.x); u.h[1]=f2bf(f0.y); u.h[2]=f2bf(f0.z); u.h[3]=f2bf(f0.w);
                u.h[4]=f2bf(f1.x); u.h[5]=f2bf(f1.y); u.h[6]=f2bf(f1.z); u.h[7]=f2bf(f1.w);
                u.h[8]=f2bf(f2.x); u.h[9]=f2bf(f2.y); u.h[10]=f2bf(f2.z); u.h[11]=f2bf(f2.w);
                u.h[12]=f2bf(f3.x); u.h[13]=f2bf(f3.y); u.h[14]=f2bf(f3.z); u.h[15]=f2bf(f3.w);
                b0 = u.v[0]; b1 = u.v[1];
            } else {
                const u16* bp = (const u16*)Bsrc + (size_t)c * K + k0 + half * 16;
                b0 = *(const u32x4*)(bp);
                b1 = *(const u32x4*)(bp + 8);
            }
        }
        __syncthreads();                    // previous compute done before overwrite
        *(u32x4*)&As[i * 40 + half * 16]     = a0;
        *(u32x4*)&As[i * 40 + half * 16 + 8] = a1;
        *(u32x4*)&Bs[i * 40 + half * 16]     = b0;
        *(u32x4*)&Bs[i * 40 + half * 16 + 8] = b1;
        __syncthreads();

        bf16x8 av[4], bv[4];
#pragma unroll
        for (int mi = 0; mi < 4; mi++)
            av[mi] = *(const bf16x8*)&As[(m0 + mi * 16 + n16) * 40 + quad * 8];
#pragma unroll
        for (int ni = 0; ni < 4; ni++)
            bv[ni] = *(const bf16x8*)&Bs[(n0 + ni * 16 + n16) * 40 + quad * 8];
#pragma unroll
        for (int mi = 0; mi < 4; mi++)
#pragma unroll
            for (int ni = 0; ni < 4; ni++)
                acc[mi][ni] = __builtin_amdgcn_mfma_f32_16x16x32_bf16(
                    av[mi], bv[ni], acc[mi][ni], 0, 0, 0);
    }

    __syncthreads();
    if (EPI == 0) {
#pragma unroll
        for (int mi = 0; mi < 4; mi++)
#pragma unroll
            for (int ni = 0; ni < 4; ni++)
#pragma unroll
                for (int r = 0; r < 4; r++) {
                    int row = rbase + m0 + mi * 16 + quad * 4 + r;
                    int col = cbase + n0 + ni * 16 + n16;
                    if (row < M && col < N)
                        outB[(size_t)row * ldo + col] = f2bf(acc[mi][ni][r]);
                }
    } else if (EPI == 3) {
        // fp32 out + bias: gsum = out matrix [M x ldo], gsel = bias[N]
#pragma unroll
        for (int mi = 0; mi < 4; mi++)
#pragma unroll
            for (int ni = 0; ni < 4; ni++)
#pragma unroll
                for (int r = 0; r < 4; r++) {
                    int row = rbase + m0 + mi * 16 + quad * 4 + r;
                    int col = cbase + n0 + ni * 16 + n16;
                    if (row < M && col < N)
                        gsum[(size_t)row * ldo + col] = acc[mi][ni][r] + gsel[col];
                }
    } else {
#pragma unroll
        for (int mi = 0; mi < 4; mi++)
#pragma unroll
            for (int r = 0; r < 4; r++) {
                int lrow = m0 + mi * 16 + quad * 4 + r;
                int nid = rown[lrow];
                float s = 0.f;
                if (nid >= 0) {
                    int sc = (EPI == 1) ? selcol[nid] : (targets[nid] - lo);
#pragma unroll
                    for (int ni = 0; ni < 4; ni++) {
                        int col = cbase + n0 + ni * 16 + n16;
                        if (col < N) {
                            float v = acc[mi][ni][r];
                            s += __expf(v);
                            if (col == sc) gsel[nid] = v;
                        }
                    }
                }
                s += __shfl_xor(s, 1);
                s += __shfl_xor(s, 2);
                s += __shfl_xor(s, 4);
                s += __shfl_xor(s, 8);
                if (n16 == 0) redl[lrow * 2 + (wid & 1)] = s;
            }
        __syncthreads();
        if (tid < 128) {
            int nid = rown[tid];
            if (nid >= 0) atomicAdd(&gsum[nid], redl[tid * 2] + redl[tid * 2 + 1]);
        }
    }
}

// ---------------------------------------------------------------------------
// Persistent MFMA GRU: 64 blocks x 128 threads. Round-1 proven skeleton:
// per-block flag line (own LLC line, stride-32 ints), wave-parallel 64-line
// poll, BULK load + MFMA (one pipelined batch). Two bounded additions:
// (1) deferred ys/hT stores + next-step xp prefetch AFTER the flag publish
//     (off the pre-publish waitcnt drain);
// (2) 2-batch snapshot consume: one flag snapshot at step top; ready chunks
//     consumed as batch 1 (bulk, pipelined), then spin until ALL flags >= t
//     (cheap ballot test), then batch 2 = remainder. At most 2 rounds.
// Double-buffer safety: h WRITES still gated on observing all flags >= t
// (spin completes before epilogue in every path) — identical barrier
// semantics to the proven round-1 kernel; only reads start early.
__global__ void __launch_bounds__(128, 1)
gru_persist_k(const float* __restrict__ xp, const float* __restrict__ hidden,
              u16* __restrict__ hb0, u16* __restrict__ hb1,
              const float* __restrict__ w_hh, const float* __restrict__ b_hh,
              const int* __restrict__ lengths, u16* __restrict__ ys,
              float* __restrict__ hT, int* __restrict__ flags)
{
    __shared__ u16 Blds[48 * 1032];          // 97 KB, row = g*16+c, +8 pad
    const int tid = threadIdx.x;
    const int bid = blockIdx.x;
    const int j0 = bid * 16;
    const int lane = tid & 63, wid = tid >> 6;
    const int n16 = lane & 15, quad = lane >> 4;

    for (int idx = tid; idx < 48 * 1024; idx += 128) {
        int r = idx >> 10, k = idx & 1023;
        int g = r >> 4, c = r & 15;
        Blds[r * 1032 + k] = f2bf(w_hh[(size_t)(g * HD + j0 + c) * HD + k]);
    }

    const int col = j0 + n16;
    float bh0 = b_hh[col], bh1 = b_hh[HD + col], bh2 = b_hh[2 * HD + col];
    float hold[4];
    int len[4];
#pragma unroll
    for (int r = 0; r < 4; r++) {
        int b = wid * 16 + quad * 4 + r;
        len[r] = lengths[b];
        hold[r] = hidden[b * HD + col];
    }
    __syncthreads();

    // prefetch xp for t = 0
    float xrv[4], xzv[4], xnv[4];
#pragma unroll
    for (int r = 0; r < 4; r++) {
        int b = wid * 16 + quad * 4 + r;
        const float* xpt = xp + (size_t)b * G3 + col;
        xrv[r] = xpt[0]; xzv[r] = xpt[HD]; xnv[r] = xpt[2 * HD];
    }

    const int boff = n16 * 1032 + quad * 8;
    const size_t rowoff = (size_t)(wid * 16 + n16) * HD + quad * 8;

    for (int t = 0; t < TT - 1; t++) {
        const u16* hbR = (t & 1) ? hb1 : hb0;
        u16* hbW = (t & 1) ? hb0 : hb1;

        f32x4 acc0 = {0.f, 0.f, 0.f, 0.f}, acc1 = acc0, acc2 = acc0;
        u64 apf[64];

        // ---- snapshot: which producer pairs are already done? ----
        int fl = __hip_atomic_load(&flags[lane * 32], __ATOMIC_RELAXED,
                                   __HIP_MEMORY_SCOPE_AGENT);
        u64 rdy = __ballot(fl >= t);
        unsigned done = 0;

        if (rdy != ~0ull) {
            // batch 1: consume snapshot-ready chunks (bulk, pipelined)
            u64 q = rdy & (rdy >> 1);
            unsigned r0 = 0;
#pragma unroll
            for (int ks = 0; ks < 32; ks++)
                r0 |= (unsigned)((q >> (2 * ks)) & 1ull) << ks;
            r0 = __builtin_amdgcn_readfirstlane(r0);
            asm volatile("" ::: "memory");
            if (r0) {
#pragma unroll
                for (int ks = 0; ks < 32; ks++)
                    if (r0 & (1u << ks)) {
                        const u16* ap = hbR + rowoff + ks * 32;
                        apf[2*ks]   = __hip_atomic_load((const u64*)ap,
                                          __ATOMIC_RELAXED, __HIP_MEMORY_SCOPE_AGENT);
                        apf[2*ks+1] = __hip_atomic_load((const u64*)(ap + 4),
                                          __ATOMIC_RELAXED, __HIP_MEMORY_SCOPE_AGENT);
                    }
#pragma unroll
                for (int ks = 0; ks < 32; ks++)
                    if (r0 & (1u << ks)) {
                        ull2s av2; av2.x = apf[2*ks]; av2.y = apf[2*ks+1];
                        bf16x8 av = __builtin_bit_cast(bf16x8, av2);
                        bf16x8 b0 = *(const bf16x8*)&Blds[boff + ks*32];
                        bf16x8 b1 = *(const bf16x8*)&Blds[16*1032 + boff + ks*32];
                        bf16x8 b2 = *(const bf16x8*)&Blds[32*1032 + boff + ks*32];
                        acc0 = __builtin_amdgcn_mfma_f32_16x16x32_bf16(av, b0, acc0, 0, 0, 0);
                        acc1 = __builtin_amdgcn_mfma_f32_16x16x32_bf16(av, b1, acc1, 0, 0, 0);
                        acc2 = __builtin_amdgcn_mfma_f32_16x16x32_bf16(av, b2, acc2, 0, 0, 0);
                    }
                done = r0;
            }
            // wait until ALL producers published step t (cheap ballot test)
            int guard = 0;
            while (true) {
                fl = __hip_atomic_load(&flags[lane * 32], __ATOMIC_RELAXED,
                                       __HIP_MEMORY_SCOPE_AGENT);
                if (__ballot(fl >= t) == ~0ull) break;
                if (++guard >= (1 << 20)) break;
                __builtin_amdgcn_s_sleep(1);
            }
        }
        asm volatile("" ::: "memory");

        // ---- batch 2 (or the whole thing on the fast path) ----
        if (done == 0u) {
            // round-1 straight-line bulk path
#pragma unroll
            for (int ks = 0; ks < 32; ks++) {
                const u16* ap = hbR + rowoff + ks * 32;
                apf[2*ks]   = __hip_atomic_load((const u64*)ap,
                                  __ATOMIC_RELAXED, __HIP_MEMORY_SCOPE_AGENT);
                apf[2*ks+1] = __hip_atomic_load((const u64*)(ap + 4),
                                  __ATOMIC_RELAXED, __HIP_MEMORY_SCOPE_AGENT);
            }
#pragma unroll
            for (int ks = 0; ks < 32; ks++) {
                ull2s av2; av2.x = apf[2*ks]; av2.y = apf[2*ks+1];
                bf16x8 av = __builtin_bit_cast(bf16x8, av2);
                bf16x8 b0 = *(const bf16x8*)&Blds[boff + ks*32];
                bf16x8 b1 = *(const bf16x8*)&Blds[16*1032 + boff + ks*32];
                bf16x8 b2 = *(const bf16x8*)&Blds[32*1032 + boff + ks*32];
                acc0 = __builtin_amdgcn_mfma_f32_16x16x32_bf16(av, b0, acc0, 0, 0, 0);
                acc1 = __builtin_amdgcn_mfma_f32_16x16x32_bf16(av, b1, acc1, 0, 0, 0);
                acc2 = __builtin_amdgcn_mfma_f32_16x16x32_bf16(av, b2, acc2, 0, 0, 0);
            }
        } else {
            unsigned rem = ~done;
#pragma unroll
            for (int ks = 0; ks < 32; ks++)
                if (rem & (1u << ks)) {
                    const u16* ap = hbR + rowoff + ks * 32;
                    apf[2*ks]   = __hip_atomic_load((const u64*)ap,
                                      __ATOMIC_RELAXED, __HIP_MEMORY_SCOPE_AGENT);
                    apf[2*ks+1] = __hip_atomic_load((const u64*)(ap + 4),
                                      __ATOMIC_RELAXED, __HIP_MEMORY_SCOPE_AGENT);
                }
#pragma unroll
            for (int ks = 0; ks < 32; ks++)
                if (rem & (1u << ks)) {
                    ull2s av2; av2.x = apf[2*ks]; av2.y = apf[2*ks+1];
                    bf16x8 av = __builtin_bit_cast(bf16x8, av2);
                    bf16x8 b0 = *(const bf16x8*)&Blds[boff + ks*32];
                    bf16x8 b1 = *(const bf16x8*)&Blds[16*1032 + boff + ks*32];
                    bf16x8 b2 = *(const bf16x8*)&Blds[32*1032 + boff + ks*32];
                    acc0 = __builtin_amdgcn_mfma_f32_16x16x32_bf16(av, b0, acc0, 0, 0, 0);
                    acc1 = __builtin_amdgcn_mfma_f32_16x16x32_bf16(av, b1, acc1, 0, 0, 0);
                    acc2 = __builtin_amdgcn_mfma_f32_16x16x32_bf16(av, b2, acc2, 0, 0, 0);
                }
        }

        // ---- epilogue: gates + h store ----
        float ysv[4];
#pragma unroll
        for (int r = 0; r < 4; r++) {
            int b = wid * 16 + quad * 4 + r;
            float hr = acc0[r] + bh0, hz = acc1[r] + bh1, hn = acc2[r] + bh2;
            float rg = 1.f / (1.f + __expf(-(xrv[r] + hr)));
            float zg = 1.f / (1.f + __expf(-(xzv[r] + hz)));
            float nv = tanhf(xnv[r] + rg * hn);
            bool valid = t < (len[r] - 1);
            float hnew = valid ? (1.f - zg) * nv + zg * hold[r] : hold[r];
            hold[r] = hnew;
            ysv[r] = valid ? hnew : 0.f;
            __hip_atomic_store(hbW + (size_t)b * HD + col, f2bf(hnew),
                               __ATOMIC_RELAXED, __HIP_MEMORY_SCOPE_AGENT);
        }

        // ---- publish: h stores drained (both waves), then own flag ----
        __builtin_amdgcn_s_waitcnt(0);
        __syncthreads();
        if (tid == 0)
            __hip_atomic_store(&flags[bid * 32], t + 1, __ATOMIC_RELAXED,
                               __HIP_MEMORY_SCOPE_AGENT);

        // ---- deferred (overlaps other blocks' publishes): ys/hT + xp prefetch ----
#pragma unroll
        for (int r = 0; r < 4; r++) {
            int b = wid * 16 + quad * 4 + r;
            ys[((size_t)b * 127 + t) * HD + col] = f2bf(ysv[r]);
            if (t == TT - 2) hT[b * HD + col] = hold[r];
        }
        const int tn = (t < TT - 2) ? t + 1 : t;   // clamped prefetch
#pragma unroll
        for (int r = 0; r < 4; r++) {
            int b = wid * 16 + quad * 4 + r;
            const float* xpt = xp + ((size_t)tn * BBATCH + b) * G3 + col;
            xrv[r] = xpt[0]; xzv[r] = xpt[HD]; xnv[r] = xpt[2 * HD];
        }
    }
}

// ---------------------------------------------------------------------------
__global__ void finish_k(const float* __restrict__ hsum, const float* __restrict__ hsel,
                         const float* __restrict__ t1sum, const float* __restrict__ t1sel,
                         const float* __restrict__ t2sum, const float* __restrict__ t2sel,
                         const int* __restrict__ targets, float* __restrict__ losssum)
{
    __shared__ float red[256];
    int n = blockIdx.x * 256 + threadIdx.x;
    float lp = 0.f;
    if (n < NR) {
        lp = hsel[n] - logf(hsum[n]);
        int tgt = targets[n];
        if (tgt >= CC1)      lp += t2sel[n] - logf(t2sum[n]);
        else if (tgt >= CC0) lp += t1sel[n] - logf(t1sum[n]);
    }
    red[threadIdx.x] = lp;
    __syncthreads();
    for (int s = 128; s > 0; s >>= 1) {
        if (threadIdx.x < s) red[threadIdx.x] += red[threadIdx.x + s];
        __syncthreads();
    }
    if (threadIdx.x == 0) atomicAdd(losssum, red[0]);
}

__global__ void out_k(const float* __restrict__ losssum, const float* __restrict__ hT,
                      float* __restrict__ out)
{
    int i = blockIdx.x * 256 + threadIdx.x;
    if (i == 0) out[0] = -losssum[0] / (float)NR;
    if (i < BBATCH * HD) out[1 + i] = hT[i];
}

// ---------------------------------------------------------------------------
extern "C" void kernel_launch(void* const* d_in, const int* in_sizes, int n_in,
                              void* d_out, int out_size, void* d_ws, size_t ws_size,
                              hipStream_t stream)
{
    const int*   x       = (const int*)d_in[0];
    const int*   lengths = (const int*)d_in[1];
    const float* hidden  = (const float*)d_in[2];
    const float* emb     = (const float*)d_in[3];
    const float* w_ih    = (const float*)d_in[4];
    const float* w_hh    = (const float*)d_in[5];
    const float* b_ih    = (const float*)d_in[6];
    const float* b_hh    = (const float*)d_in[7];
    const float* head_w  = (const float*)d_in[8];
    const float* p1      = (const float*)d_in[9];
    const float* t1      = (const float*)d_in[10];
    const float* p2      = (const float*)d_in[11];
    const float* t2      = (const float*)d_in[12];

    float* ws = (float*)d_ws;
    float* xp    = ws + OFF_XP;
    u16*   ysb   = (u16*)(ws + OFF_YSB);
    u16*   hb0   = (u16*)(ws + OFF_HB);
    u16*   hb1   = hb0 + BBATCH * HD;
    float* hT    = ws + OFF_HT;
    u16*   p1b   = (u16*)(ws + OFF_P1B);   // proj1 bf16 out
    u16*   p2b   = (u16*)(ws + OFF_P2B);   // proj2 bf16 out
    u16*   whb   = (u16*)(ws + OFF_WHB);   // head_w bf16
    u16*   t1b   = (u16*)(ws + OFF_T1B);   // t1 bf16
    u16*   pp1b  = (u16*)(ws + OFF_PP1);   // p1 bf16
    u16*   pp2b  = (u16*)(ws + OFF_PP2);   // p2 bf16
    float* hsum  = ws + OFF_SUM;
    float* hsel  = hsum + 4064;
    float* t1sum = hsel + 4064;
    float* t1sel = t1sum + 4064;
    float* t2sum = t1sel + 4064;
    float* t2sel = t2sum + 4064;
    float* losss = ws + OFF_LOSS;
    int* ib      = (int*)(ws + OFF_INT);
    int* targets = ib;
    int* hselc   = ib + 4064;
    int* list1   = ib + 2 * 4064;
    int* list2   = ib + 3 * 4064;
    int* cnt1    = ib + 4 * 4064;
    int* cnt2    = cnt1 + 1;
    int* flags   = ib + 5 * 4064;    // 64 flags x 32-int stride (zeroed by init)

    // time-disjoint aliases
    u16* embA = (u16*)(ws + OFF_YSB);  // bf16 A for xp GEMM (dead before GRU writes ys)
    u16* wihb = (u16*)(ws + OFF_WIHB); // bf16 w_ih scratch
    u16* t2b  = (u16*)(ws + OFF_XP);   // bf16 t2 (converted after GRU; xp dead)

    float* out = (float*)d_out;

    init_k<<<232, 256, 0, stream>>>(hidden, hb0, hsum, cnt1, cnt2, flags);
    prep_k<<<16, 256, 0, stream>>>(x, targets, hselc, list1, list2, cnt1, cnt2);

    // all fp32->bf16 weight converts in one launch:
    // w_ih (393216), head_w (512512), t1 (512000), p1 (65536), p2 (16384)
    cvt_multi_k<<<(1499648 + 255) / 256, 256, 0, stream>>>(
        w_ih, wihb, 393216,
        head_w, whb, 512512,
        t1, t1b, 512000,
        p1, pp1b, 65536,
        p2, pp2b, 16384);

    // xp = embed(x) @ w_ih^T + b_ih   [4064 x 3072] fp32, via bf16 MFMA
    emb_gather_k<<<(NR * 64 + 255) / 256, 256, 0, stream>>>(x, emb, embA);
    mfma_gemm_k<3, 0><<<dim3(32, 24), 256, 0, stream>>>(
        embA, wihb, NR, G3, ED, nullptr, nullptr, nullptr, G3,
        xp, (float*)b_ih, nullptr, nullptr, 0);

    // GRU recurrence: persistent MFMA kernel, flag-array barrier + 2-batch consume
    gru_persist_k<<<NBG, 128, 0, stream>>>(xp, hidden, hb0, hb1, w_hh, b_hh,
                                           lengths, ysb, hT, flags);

    // t2 fp32 -> bf16 once (into now-dead xp region): tail2 B traffic halves
    cvt_bf16_k<<<(640000 + 255) / 256, 256, 0, stream>>>(t2, t2b, 640000);

    // proj1 = ys @ p1^T  -> bf16 [4064 x 256]
    mfma_gemm_k<0, 0><<<dim3(32, 2), 256, 0, stream>>>(
        ysb, pp1b, NR, HH1, HD, nullptr, nullptr, p1b, HH1,
        nullptr, nullptr, nullptr, nullptr, 0);
    // proj2 = ys @ p2^T  -> bf16 [4064 x 64]
    mfma_gemm_k<0, 0><<<dim3(32, 1), 256, 0, stream>>>(
        ysb, pp2b, NR, HH2, HD, nullptr, nullptr, p2b, HH2,
        nullptr, nullptr, nullptr, nullptr, 0);
    // head: exp-sum + selected logit
    mfma_gemm_k<1, 0><<<dim3(32, 16), 256, 0, stream>>>(
        ysb, whb, NR, CC0 + 2, HD, nullptr, nullptr, nullptr, 0,
        hsum, hsel, hselc, nullptr, 0);
    // tail1 over compacted rows
    mfma_gemm_k<2, 0><<<dim3(32, 63), 256, 0, stream>>>(
        p1b, t1b, 0, SS1, HH1, list1, cnt1, nullptr, 0,
        t1sum, t1sel, nullptr, targets, CC0);
    // tail2 over compacted rows, B = pre-converted bf16 t2
    mfma_gemm_k<2, 0><<<dim3(32, 313), 256, 0, stream>>>(
        p2b, t2b, 0, SS2, HH2, list2, cnt2, nullptr, 0,
        t2sum, t2sel, nullptr, targets, CC1);

    finish_k<<<16, 256, 0, stream>>>(hsum, hsel, t1sum, t1sel, t2sum, t2sel,
                                     targets, losss);
    out_k<<<128, 256, 0, stream>>>(losss, hT, out);
}

// Round 7
// 1353.698 us; speedup vs baseline: 1.3187x; 1.1825x over previous
//
#include <hip/hip_runtime.h>
#include <math.h>

// Problem constants
#define VV   50000
#define CC0  2000
#define CC1  10000
#define ED   512
#define HD   1024
#define BBATCH 32
#define TT   128
#define HH1  256
#define HH2  64
#define SS1  8000
#define SS2  40000
#define NR   4064        // B*(T-1) = 32*127; canonical row index n' = t*32 + b
#define G3   3072        // 3*H

// Workspace layout (offsets in floats).
// Aliases (time-disjoint):
//   embA (bf16 4064x512)  @ OFF_YSB  -- dead once xp GEMM done; ysb written by GRU later
//   wihb (bf16 3072x512)  @ OFF_WIHB -- scratch, only used by xp GEMM
//   t2b  (bf16 40000x64)  @ OFF_XP   -- converted after fused kernel (xp dead), used by tail2
#define OFF_XP   0ull                      // xp fp32: 12,484,608
#define OFF_YSB  12484608ull               // ys bf16: 4,161,536 u16 = 2,080,768 fl
#define OFF_HB   14565376ull               // hb0+hb1: 65,536 u16 = 32,768 fl
#define OFF_HT   14598144ull               // hT fp32: 32,768
#define OFF_P1B  14630912ull               // proj1 bf16: 520,192 fl
#define OFF_P2B  15151104ull               // proj2 bf16: 130,048 fl
#define OFF_WHB  15281152ull               // head_w bf16: 1,025,024 fl
#define OFF_T1B  16306176ull               // t1 bf16: 1,024,000 fl
#define OFF_PP1  17330176ull               // p1 bf16: 131,072 fl
#define OFF_PP2  17461248ull               // p2 bf16: 32,768 fl
#define OFF_SUM  17494016ull               // 6*4064 floats
#define OFF_LOSS (OFF_SUM + 6ull*4064ull)  // 64 floats
#define OFF_INT  (OFF_LOSS + 64ull)        // ints: targets,hselc,list1,list2,cnt,flags
#define OFF_WIHB (OFF_INT + 8ull*4064ull)  // w_ih bf16 scratch: 786,432 fl

#define ZERO_N (6*4064 + 64)
#define NBG 64            // GRU producer blocks
#define NCONS 192         // consumer blocks (64+192 = 256 = CU count, 1 block/CU)
#define NTILES 608        // 512 head + 64 proj1 + 32 proj2

typedef __attribute__((ext_vector_type(8))) __bf16 bf16x8;
typedef __attribute__((ext_vector_type(4))) float f32x4;
typedef __attribute__((ext_vector_type(4))) unsigned int u32x4;
typedef unsigned long long u64;
typedef unsigned short u16;
struct ull2s { u64 x, y; };

__device__ __forceinline__ u16 f2bf(float f) {
    unsigned u = __builtin_bit_cast(unsigned, f);
    u += 0x7fff + ((u >> 16) & 1);          // round-to-nearest-even
    return (u16)(u >> 16);
}

// ---------------------------------------------------------------------------
// init: h0 -> bf16 buffer, zero the sum/loss region, counters, flag lines
__global__ void init_k(const float* __restrict__ hidden, u16* __restrict__ hb0,
                       float* __restrict__ zreg, int* __restrict__ cnt1,
                       int* __restrict__ cnt2, int* __restrict__ bar)
{
    int i = blockIdx.x * 256 + threadIdx.x;
    if (i < BBATCH * HD) hb0[i] = f2bf(hidden[i]);
    int zi = i - BBATCH * HD;
    if (zi >= 0 && zi < ZERO_N) zreg[zi] = 0.f;
    if (zi == ZERO_N) { *cnt1 = 0; *cnt2 = 0; }
    int bi = zi - (ZERO_N + 1);
    if (bi >= 0 && bi < 2048) bar[bi] = 0;
}

// prep: targets, head sel-cols, cluster row lists -- all in n' = t*32+b order
__global__ void prep_k(const int* __restrict__ x, int* __restrict__ targets,
                       int* __restrict__ hselc, int* __restrict__ list1,
                       int* __restrict__ list2, int* __restrict__ cnt1, int* __restrict__ cnt2)
{
    int n = blockIdx.x * 256 + threadIdx.x;
    if (n >= NR) return;
    int t = n >> 5, b = n & 31;
    int tgt = x[b * TT + t + 1];
    targets[n] = tgt;
    hselc[n] = (tgt < CC0) ? tgt : ((tgt < CC1) ? CC0 : CC0 + 1);
    if (tgt >= CC0 && tgt < CC1) list1[atomicAdd(cnt1, 1)] = n;
    else if (tgt >= CC1)         list2[atomicAdd(cnt2, 1)] = n;
}

// fp32 -> bf16 convert (n4 float4 groups)
__global__ void cvt_bf16_k(const float* __restrict__ src, u16* __restrict__ dst, int n4)
{
    int i = blockIdx.x * 256 + threadIdx.x;
    if (i >= n4) return;
    float4 f = *(const float4*)(src + 4 * (size_t)i);
    union { u16 h[4]; u64 v; } u;
    u.h[0] = f2bf(f.x); u.h[1] = f2bf(f.y); u.h[2] = f2bf(f.z); u.h[3] = f2bf(f.w);
    *(u64*)&dst[4 * (size_t)i] = u.v;
}

// fused fp32 -> bf16 convert over 5 weight buffers (one launch)
__global__ void cvt_multi_k(const float* __restrict__ s0, u16* __restrict__ d0, int n0,
                            const float* __restrict__ s1, u16* __restrict__ d1, int n1,
                            const float* __restrict__ s2, u16* __restrict__ d2, int n2,
                            const float* __restrict__ s3, u16* __restrict__ d3, int n3,
                            const float* __restrict__ s4, u16* __restrict__ d4, int n4)
{
    int i = blockIdx.x * 256 + threadIdx.x;
    const float* s; u16* d; int off = i;
    if (off < n0) { s = s0; d = d0; }
    else if ((off -= n0) < n1) { s = s1; d = d1; }
    else if ((off -= n1) < n2) { s = s2; d = d2; }
    else if ((off -= n2) < n3) { s = s3; d = d3; }
    else if ((off -= n3) < n4) { s = s4; d = d4; }
    else return;
    float4 f = *(const float4*)(s + 4 * (size_t)off);
    union { u16 h[4]; u64 v; } u;
    u.h[0] = f2bf(f.x); u.h[1] = f2bf(f.y); u.h[2] = f2bf(f.z); u.h[3] = f2bf(f.w);
    *(u64*)&d[4 * (size_t)off] = u.v;
}

// gather used embedding rows -> compact bf16 A matrix, row n' = t*32+b
__global__ void emb_gather_k(const int* __restrict__ x, const float* __restrict__ emb,
                             u16* __restrict__ embA)
{
    int idx = blockIdx.x * 256 + threadIdx.x;   // NR*64 threads, 8 floats each
    if (idx >= NR * 64) return;
    int n = idx >> 6;
    int kk = (idx & 63) << 3;
    int b = n & 31, t = n >> 5;
    int tok = x[b * TT + t];
    const float* ap = emb + (size_t)tok * ED + kk;
    float4 f0 = *(const float4*)ap;
    float4 f1 = *(const float4*)(ap + 4);
    union { u16 h[8]; u32x4 v; } u;
    u.h[0] = f2bf(f0.x); u.h[1] = f2bf(f0.y); u.h[2] = f2bf(f0.z); u.h[3] = f2bf(f0.w);
    u.h[4] = f2bf(f1.x); u.h[5] = f2bf(f1.y); u.h[6] = f2bf(f1.z); u.h[7] = f2bf(f1.w);
    *(u32x4*)&embA[(size_t)n * ED + kk] = u.v;
}

// ---------------------------------------------------------------------------
// bf16 MFMA GEMM, 128x128 tile, BK=32, 4 waves (2x2 of 64x64).
// EPI 2: tail exp-sum over compacted rows. EPI 3: fp32 out + bias.
template<int EPI, int BFP32>
__global__ void __launch_bounds__(256)
mfma_gemm_k(const u16* __restrict__ Ab, const void* __restrict__ Bsrc,
            int Mdirect, int N, int K,
            const int* __restrict__ rowmap, const int* __restrict__ cntp,
            u16* __restrict__ outB, int ldo,
            float* __restrict__ gsum, float* __restrict__ gsel,
            const int* __restrict__ selcol, const int* __restrict__ targets, int lo)
{
    const int M = cntp ? *cntp : Mdirect;
    const int rbase = blockIdx.x * 128;
    if (rbase >= M) return;
    const int cbase = blockIdx.y * 128;

    __shared__ u16 As[128 * 40];
    __shared__ u16 Bs[128 * 40];
    __shared__ const u16* aptr[128];
    __shared__ int rown[128];
    __shared__ float redl[128 * 2];

    const int tid = threadIdx.x;
    if (tid < 128) {
        int rid = -1;
        if (rbase + tid < M) rid = rowmap ? rowmap[rbase + tid] : (rbase + tid);
        rown[tid] = rid;
        aptr[tid] = (rid >= 0) ? (Ab + (size_t)rid * K) : nullptr;
    }
    __syncthreads();

    const int lane = tid & 63, wid = tid >> 6;
    const int n16 = lane & 15, quad = lane >> 4;
    const int m0 = (wid >> 1) * 64, n0 = (wid & 1) * 64;
    const int i = tid >> 1, half = tid & 1;

    f32x4 acc[4][4];
#pragma unroll
    for (int a = 0; a < 4; a++)
#pragma unroll
        for (int b = 0; b < 4; b++) acc[a][b] = (f32x4){0.f, 0.f, 0.f, 0.f};

    for (int k0 = 0; k0 < K; k0 += 32) {
        const u16* ap = aptr[i];
        u32x4 a0 = {0,0,0,0}, a1 = a0;
        if (ap) {
            a0 = *(const u32x4*)(ap + k0 + half * 16);
            a1 = *(const u32x4*)(ap + k0 + half * 16 + 8);
        }
        u32x4 b0 = {0,0,0,0}, b1 = b0;
        int c = cbase + i;
        if (c < N) {
            if (BFP32) {
                const float* bp = (const float*)Bsrc + (size_t)c * K + k0 + half * 16;
                float4 f0 = *(const float4*)(bp);
                float4 f1 = *(const float4*)(bp + 4);
                float4 f2 = *(const float4*)(bp + 8);
                float4 f3 = *(const float4*)(bp + 12);
                union { u16 h[16]; u32x4 v[2]; } u;
                u.h[0]=f2bf(f0.x); u.h[1]=f2bf(f0.y); u.h[2]=f2bf(f0.z); u.h[3]=f2bf(f0.w);
                u.h[4]=f2bf(f1.x); u.h[5]=f2bf(f1.y); u.h[6]=f2bf(f1.z); u.h[7]=f2bf(f1.w);
                u.h[8]=f2bf(f2.x); u.h[9]=f2bf(f2.y); u.h[10]=f2bf(f2.z); u.h[11]=f2bf(f2.w);
                u.h[12]=f2bf(f3.x); u.h[13]=f2bf(f3.y); u.h[14]=f2bf(f3.z); u.h[15]=f2bf(f3.w);
                b0 = u.v[0]; b1 = u.v[1];
            } else {
                const u16* bp = (const u16*)Bsrc + (size_t)c * K + k0 + half * 16;
                b0 = *(const u32x4*)(bp);
                b1 = *(const u32x4*)(bp + 8);
            }
        }
        __syncthreads();
        *(u32x4*)&As[i * 40 + half * 16]     = a0;
        *(u32x4*)&As[i * 40 + half * 16 + 8] = a1;
        *(u32x4*)&Bs[i * 40 + half * 16]     = b0;
        *(u32x4*)&Bs[i * 40 + half * 16 + 8] = b1;
        __syncthreads();

        bf16x8 av[4], bv[4];
#pragma unroll
        for (int mi = 0; mi < 4; mi++)
            av[mi] = *(const bf16x8*)&As[(m0 + mi * 16 + n16) * 40 + quad * 8];
#pragma unroll
        for (int ni = 0; ni < 4; ni++)
            bv[ni] = *(const bf16x8*)&Bs[(n0 + ni * 16 + n16) * 40 + quad * 8];
#pragma unroll
        for (int mi = 0; mi < 4; mi++)
#pragma unroll
            for (int ni = 0; ni < 4; ni++)
                acc[mi][ni] = __builtin_amdgcn_mfma_f32_16x16x32_bf16(
                    av[mi], bv[ni], acc[mi][ni], 0, 0, 0);
    }

    __syncthreads();
    if (EPI == 0) {
#pragma unroll
        for (int mi = 0; mi < 4; mi++)
#pragma unroll
            for (int ni = 0; ni < 4; ni++)
#pragma unroll
                for (int r = 0; r < 4; r++) {
                    int row = rbase + m0 + mi * 16 + quad * 4 + r;
                    int col = cbase + n0 + ni * 16 + n16;
                    if (row < M && col < N)
                        outB[(size_t)row * ldo + col] = f2bf(acc[mi][ni][r]);
                }
    } else if (EPI == 3) {
#pragma unroll
        for (int mi = 0; mi < 4; mi++)
#pragma unroll
            for (int ni = 0; ni < 4; ni++)
#pragma unroll
                for (int r = 0; r < 4; r++) {
                    int row = rbase + m0 + mi * 16 + quad * 4 + r;
                    int col = cbase + n0 + ni * 16 + n16;
                    if (row < M && col < N)
                        gsum[(size_t)row * ldo + col] = acc[mi][ni][r] + gsel[col];
                }
    } else {
#pragma unroll
        for (int mi = 0; mi < 4; mi++)
#pragma unroll
            for (int r = 0; r < 4; r++) {
                int lrow = m0 + mi * 16 + quad * 4 + r;
                int nid = rown[lrow];
                float s = 0.f;
                if (nid >= 0) {
                    int sc = (EPI == 1) ? selcol[nid] : (targets[nid] - lo);
#pragma unroll
                    for (int ni = 0; ni < 4; ni++) {
                        int col = cbase + n0 + ni * 16 + n16;
                        if (col < N) {
                            float v = acc[mi][ni][r];
                            s += __expf(v);
                            if (col == sc) gsel[nid] = v;
                        }
                    }
                }
                s += __shfl_xor(s, 1);
                s += __shfl_xor(s, 2);
                s += __shfl_xor(s, 4);
                s += __shfl_xor(s, 8);
                if (n16 == 0) redl[lrow * 2 + (wid & 1)] = s;
            }
        __syncthreads();
        if (tid < 128) {
            int nid = rown[tid];
            if (nid >= 0) atomicAdd(&gsum[nid], redl[tid * 2] + redl[tid * 2 + 1]);
        }
    }
}

// ---------------------------------------------------------------------------
// FUSED persistent kernel: 256 blocks x 256 threads (1 block/CU via LDS).
// Blocks 0..63: the PROVEN round-1 GRU (128 active threads; 2 idle waves just
//   join barriers). ys written time-major (row n' = t*32+b) via agent-scope
//   atomic stores so consumer blocks on other XCDs see them (drained before
//   the flag publish, same mechanism as the h exchange).
// Blocks 64..255: persistent consumers. Tile g of {512 head, 64 proj1,
//   32 proj2} 128x128xK=1024 MFMA tiles; tile with row-block x covers
//   t in [4x,4x+4) and is ready when all 64 flags >= min(4x+4,127).
//   A rows (ys) read via agent-scope atomic u64 loads. All spins bounded.
__global__ void __launch_bounds__(256, 1)
gru_fused_k(const float* __restrict__ xp, const float* __restrict__ hidden,
            u16* __restrict__ hb0, u16* __restrict__ hb1,
            const float* __restrict__ w_hh, const float* __restrict__ b_hh,
            const int* __restrict__ lengths, u16* __restrict__ ys,
            float* __restrict__ hT, int* __restrict__ flags,
            const u16* __restrict__ whb, const u16* __restrict__ pp1b,
            const u16* __restrict__ pp2b, u16* __restrict__ p1b,
            u16* __restrict__ p2b, float* __restrict__ hsum,
            float* __restrict__ hsel, const int* __restrict__ hselc)
{
    __shared__ u16 Blds[48 * 1032];          // 97 KB (GRU w_hh slice)
    __shared__ u16 As[128 * 40];             // consumer staging
    __shared__ u16 Bs[128 * 40];
    __shared__ const u16* aptr[128];
    __shared__ int rown[128];
    __shared__ float redl[128 * 2];

    const int tid = threadIdx.x;
    const int lane = tid & 63;
    const int n16 = lane & 15, quad = lane >> 4;

    if (blockIdx.x < NBG) {
        // ======================= GRU producer =======================
        const int bid = blockIdx.x;
        const int j0 = bid * 16;
        const int wid = tid >> 6;            // 0..3; GRU math uses wid 0/1 only

        for (int idx = tid; idx < 48 * 1024; idx += 256) {
            int r = idx >> 10, k = idx & 1023;
            int g = r >> 4, c = r & 15;
            Blds[r * 1032 + k] = f2bf(w_hh[(size_t)(g * HD + j0 + c) * HD + k]);
        }

        const int col = j0 + n16;
        float bh0 = 0.f, bh1 = 0.f, bh2 = 0.f;
        float hold[4];
        int len[4] = {0, 0, 0, 0};
        if (tid < 128) {
            bh0 = b_hh[col]; bh1 = b_hh[HD + col]; bh2 = b_hh[2 * HD + col];
#pragma unroll
            for (int r = 0; r < 4; r++) {
                int b = wid * 16 + quad * 4 + r;
                len[r] = lengths[b];
                hold[r] = hidden[b * HD + col];
            }
        }
        __syncthreads();

        const int boff = n16 * 1032 + quad * 8;
        const size_t rowoff = (size_t)(wid * 16 + n16) * HD + quad * 8;

        for (int t = 0; t < TT - 1; t++) {
            if (tid < 128) {
                const u16* hb = (t & 1) ? hb1 : hb0;
                u16* hbn = (t & 1) ? hb0 : hb1;

                float xrv[4], xzv[4], xnv[4];
#pragma unroll
                for (int r = 0; r < 4; r++) {
                    int b = wid * 16 + quad * 4 + r;
                    const float* xpt = xp + ((size_t)t * BBATCH + b) * G3 + col;
                    xrv[r] = xpt[0]; xzv[r] = xpt[HD]; xnv[r] = xpt[2 * HD];
                }

                const u16* arow = hb + rowoff;
                u64 apf[64];
#pragma unroll
                for (int ks = 0; ks < 32; ks++) {
                    apf[2*ks]   = __hip_atomic_load((const u64*)(arow + ks*32),
                                      __ATOMIC_RELAXED, __HIP_MEMORY_SCOPE_AGENT);
                    apf[2*ks+1] = __hip_atomic_load((const u64*)(arow + ks*32 + 4),
                                      __ATOMIC_RELAXED, __HIP_MEMORY_SCOPE_AGENT);
                }

                f32x4 acc0 = {0.f, 0.f, 0.f, 0.f}, acc1 = acc0, acc2 = acc0;
#pragma unroll
                for (int ks = 0; ks < 32; ks++) {
                    ull2s av2; av2.x = apf[2*ks]; av2.y = apf[2*ks+1];
                    bf16x8 av = __builtin_bit_cast(bf16x8, av2);
                    bf16x8 b0 = *(const bf16x8*)&Blds[boff + ks*32];
                    bf16x8 b1 = *(const bf16x8*)&Blds[16*1032 + boff + ks*32];
                    bf16x8 b2 = *(const bf16x8*)&Blds[32*1032 + boff + ks*32];
                    acc0 = __builtin_amdgcn_mfma_f32_16x16x32_bf16(av, b0, acc0, 0, 0, 0);
                    acc1 = __builtin_amdgcn_mfma_f32_16x16x32_bf16(av, b1, acc1, 0, 0, 0);
                    acc2 = __builtin_amdgcn_mfma_f32_16x16x32_bf16(av, b2, acc2, 0, 0, 0);
                }

#pragma unroll
                for (int r = 0; r < 4; r++) {
                    int b = wid * 16 + quad * 4 + r;
                    float hr = acc0[r] + bh0, hz = acc1[r] + bh1, hn = acc2[r] + bh2;
                    float rg = 1.f / (1.f + __expf(-(xrv[r] + hr)));
                    float zg = 1.f / (1.f + __expf(-(xzv[r] + hz)));
                    float nv = tanhf(xnv[r] + rg * hn);
                    bool valid = t < (len[r] - 1);
                    float hnew = valid ? (1.f - zg) * nv + zg * hold[r] : hold[r];
                    hold[r] = hnew;
                    __hip_atomic_store(hbn + (size_t)b * HD + col, f2bf(hnew),
                                       __ATOMIC_RELAXED, __HIP_MEMORY_SCOPE_AGENT);
                    // ys time-major n' = t*32+b; agent-store for cross-XCD consumers
                    __hip_atomic_store(ys + ((size_t)t * BBATCH + b) * HD + col,
                                       f2bf(valid ? hnew : 0.f),
                                       __ATOMIC_RELAXED, __HIP_MEMORY_SCOPE_AGENT);
                    if (t == TT - 2) hT[b * HD + col] = hnew;
                }
            }

            // ---- round-1 distributed barrier ----
            __syncthreads();                  // drains each wave's vmem
            if (tid < 64) {
                if (tid == 0) {
                    __builtin_amdgcn_s_waitcnt(0);
                    __hip_atomic_store(&flags[bid * 32], t + 1, __ATOMIC_RELAXED,
                                       __HIP_MEMORY_SCOPE_AGENT);
                }
                int guard = 0;
                while (__hip_atomic_load(&flags[tid * 32], __ATOMIC_RELAXED,
                                         __HIP_MEMORY_SCOPE_AGENT) < t + 1
                       && guard < (1 << 20)) {
                    __builtin_amdgcn_s_sleep(1);
                    guard++;
                }
            }
            asm volatile("" ::: "memory");
            __syncthreads();
        }
    } else {
        // ======================= consumers =======================
        const int wid4 = tid >> 6;
        const int m0 = (wid4 >> 1) * 64, n0 = (wid4 & 1) * 64;
        const int i = tid >> 1, half = tid & 1;
        const int cb = blockIdx.x - NBG;

        for (int g = cb; g < NTILES; g += NCONS) {
            int x, y, N, ldo = 0, epi;
            const u16* Bp; u16* outp = nullptr;
            if (g < 512)      { x = g >> 4;  y = g & 15; N = CC0 + 2; Bp = whb;  epi = 1; }
            else if (g < 576) { int gg = g - 512; x = gg >> 1; y = gg & 1;
                                N = HH1; Bp = pp1b; outp = p1b; ldo = HH1; epi = 0; }
            else              { x = g - 576; y = 0;
                                N = HH2; Bp = pp2b; outp = p2b; ldo = HH2; epi = 0; }
            const int rbase = x * 128, cbase = y * 128;

            // readiness: rows t in [4x,4x+4) published once all flags >= tneed
            int tneed = 4 * x + 4; if (tneed > TT - 1) tneed = TT - 1;
            {
                int guard = 0;
                while (true) {
                    int f = __hip_atomic_load(&flags[lane * 32], __ATOMIC_RELAXED,
                                              __HIP_MEMORY_SCOPE_AGENT);
                    if (__ballot(f >= tneed) == ~0ull) break;
                    if (++guard >= (1 << 20)) break;
                    __builtin_amdgcn_s_sleep(8);
                }
            }
            asm volatile("" ::: "memory");

            __syncthreads();   // prev tile's epilogue done before rown overwrite
            if (tid < 128) {
                int rid = (rbase + tid < NR) ? (rbase + tid) : -1;
                rown[tid] = rid;
                aptr[tid] = (rid >= 0) ? (ys + (size_t)rid * HD) : nullptr;
            }
            __syncthreads();

            f32x4 acc[4][4];
#pragma unroll
            for (int a = 0; a < 4; a++)
#pragma unroll
                for (int b = 0; b < 4; b++) acc[a][b] = (f32x4){0.f, 0.f, 0.f, 0.f};

            for (int k0 = 0; k0 < HD; k0 += 32) {
                const u16* ap = aptr[i];
                u64 a0 = 0, a1 = 0, a2 = 0, a3 = 0;
                if (ap) {
                    const u64* p = (const u64*)(ap + k0 + half * 16);
                    a0 = __hip_atomic_load(p,     __ATOMIC_RELAXED, __HIP_MEMORY_SCOPE_AGENT);
                    a1 = __hip_atomic_load(p + 1, __ATOMIC_RELAXED, __HIP_MEMORY_SCOPE_AGENT);
                    a2 = __hip_atomic_load(p + 2, __ATOMIC_RELAXED, __HIP_MEMORY_SCOPE_AGENT);
                    a3 = __hip_atomic_load(p + 3, __ATOMIC_RELAXED, __HIP_MEMORY_SCOPE_AGENT);
                }
                u32x4 b0v = {0,0,0,0}, b1v = b0v;
                int c = cbase + i;
                if (c < N) {
                    const u16* bp = Bp + (size_t)c * HD + k0 + half * 16;
                    b0v = *(const u32x4*)(bp);
                    b1v = *(const u32x4*)(bp + 8);
                }
                __syncthreads();
                *(u64*)&As[i * 40 + half * 16]      = a0;
                *(u64*)&As[i * 40 + half * 16 + 4]  = a1;
                *(u64*)&As[i * 40 + half * 16 + 8]  = a2;
                *(u64*)&As[i * 40 + half * 16 + 12] = a3;
                *(u32x4*)&Bs[i * 40 + half * 16]     = b0v;
                *(u32x4*)&Bs[i * 40 + half * 16 + 8] = b1v;
                __syncthreads();

                bf16x8 av[4], bv[4];
#pragma unroll
                for (int mi = 0; mi < 4; mi++)
                    av[mi] = *(const bf16x8*)&As[(m0 + mi * 16 + n16) * 40 + quad * 8];
#pragma unroll
                for (int ni = 0; ni < 4; ni++)
                    bv[ni] = *(const bf16x8*)&Bs[(n0 + ni * 16 + n16) * 40 + quad * 8];
#pragma unroll
                for (int mi = 0; mi < 4; mi++)
#pragma unroll
                    for (int ni = 0; ni < 4; ni++)
                        acc[mi][ni] = __builtin_amdgcn_mfma_f32_16x16x32_bf16(
                            av[mi], bv[ni], acc[mi][ni], 0, 0, 0);
            }

            __syncthreads();
            if (epi == 0) {
#pragma unroll
                for (int mi = 0; mi < 4; mi++)
#pragma unroll
                    for (int ni = 0; ni < 4; ni++)
#pragma unroll
                        for (int r = 0; r < 4; r++) {
                            int row = rbase + m0 + mi * 16 + quad * 4 + r;
                            int col = cbase + n0 + ni * 16 + n16;
                            if (row < NR && col < N)
                                outp[(size_t)row * ldo + col] = f2bf(acc[mi][ni][r]);
                        }
            } else {
#pragma unroll
                for (int mi = 0; mi < 4; mi++)
#pragma unroll
                    for (int r = 0; r < 4; r++) {
                        int lrow = m0 + mi * 16 + quad * 4 + r;
                        int nid = rown[lrow];
                        float s = 0.f;
                        if (nid >= 0) {
                            int sc = hselc[nid];
#pragma unroll
                            for (int ni = 0; ni < 4; ni++) {
                                int col = cbase + n0 + ni * 16 + n16;
                                if (col < N) {
                                    float v = acc[mi][ni][r];
                                    s += __expf(v);
                                    if (col == sc) hsel[nid] = v;
                                }
                            }
                        }
                        s += __shfl_xor(s, 1);
                        s += __shfl_xor(s, 2);
                        s += __shfl_xor(s, 4);
                        s += __shfl_xor(s, 8);
                        if (n16 == 0) redl[lrow * 2 + (wid4 & 1)] = s;
                    }
                __syncthreads();
                if (tid < 128) {
                    int nid = rown[tid];
                    if (nid >= 0) atomicAdd(&hsum[nid], redl[tid * 2] + redl[tid * 2 + 1]);
                }
            }
        }
    }
}

// ---------------------------------------------------------------------------
__global__ void finish_k(const float* __restrict__ hsum, const float* __restrict__ hsel,
                         const float* __restrict__ t1sum, const float* __restrict__ t1sel,
                         const float* __restrict__ t2sum, const float* __restrict__ t2sel,
                         const int* __restrict__ targets, float* __restrict__ losssum)
{
    __shared__ float red[256];
    int n = blockIdx.x * 256 + threadIdx.x;
    float lp = 0.f;
    if (n < NR) {
        lp = hsel[n] - logf(hsum[n]);
        int tgt = targets[n];
        if (tgt >= CC1)      lp += t2sel[n] - logf(t2sum[n]);
        else if (tgt >= CC0) lp += t1sel[n] - logf(t1sum[n]);
    }
    red[threadIdx.x] = lp;
    __syncthreads();
    for (int s = 128; s > 0; s >>= 1) {
        if (threadIdx.x < s) red[threadIdx.x] += red[threadIdx.x + s];
        __syncthreads();
    }
    if (threadIdx.x == 0) atomicAdd(losssum, red[0]);
}

__global__ void out_k(const float* __restrict__ losssum, const float* __restrict__ hT,
                      float* __restrict__ out)
{
    int i = blockIdx.x * 256 + threadIdx.x;
    if (i == 0) out[0] = -losssum[0] / (float)NR;
    if (i < BBATCH * HD) out[1 + i] = hT[i];
}

// ---------------------------------------------------------------------------
extern "C" void kernel_launch(void* const* d_in, const int* in_sizes, int n_in,
                              void* d_out, int out_size, void* d_ws, size_t ws_size,
                              hipStream_t stream)
{
    const int*   x       = (const int*)d_in[0];
    const int*   lengths = (const int*)d_in[1];
    const float* hidden  = (const float*)d_in[2];
    const float* emb     = (const float*)d_in[3];
    const float* w_ih    = (const float*)d_in[4];
    const float* w_hh    = (const float*)d_in[5];
    const float* b_ih    = (const float*)d_in[6];
    const float* b_hh    = (const float*)d_in[7];
    const float* head_w  = (const float*)d_in[8];
    const float* p1      = (const float*)d_in[9];
    const float* t1      = (const float*)d_in[10];
    const float* p2      = (const float*)d_in[11];
    const float* t2      = (const float*)d_in[12];

    float* ws = (float*)d_ws;
    float* xp    = ws + OFF_XP;
    u16*   ysb   = (u16*)(ws + OFF_YSB);
    u16*   hb0   = (u16*)(ws + OFF_HB);
    u16*   hb1   = hb0 + BBATCH * HD;
    float* hT    = ws + OFF_HT;
    u16*   p1b   = (u16*)(ws + OFF_P1B);   // proj1 bf16 out
    u16*   p2b   = (u16*)(ws + OFF_P2B);   // proj2 bf16 out
    u16*   whb   = (u16*)(ws + OFF_WHB);   // head_w bf16
    u16*   t1b   = (u16*)(ws + OFF_T1B);   // t1 bf16
    u16*   pp1b  = (u16*)(ws + OFF_PP1);   // p1 bf16
    u16*   pp2b  = (u16*)(ws + OFF_PP2);   // p2 bf16
    float* hsum  = ws + OFF_SUM;
    float* hsel  = hsum + 4064;
    float* t1sum = hsel + 4064;
    float* t1sel = t1sum + 4064;
    float* t2sum = t1sel + 4064;
    float* t2sel = t2sum + 4064;
    float* losss = ws + OFF_LOSS;
    int* ib      = (int*)(ws + OFF_INT);
    int* targets = ib;
    int* hselc   = ib + 4064;
    int* list1   = ib + 2 * 4064;
    int* list2   = ib + 3 * 4064;
    int* cnt1    = ib + 4 * 4064;
    int* cnt2    = cnt1 + 1;
    int* flags   = ib + 5 * 4064;    // 64 flags x 32-int stride (zeroed by init)

    // time-disjoint aliases
    u16* embA = (u16*)(ws + OFF_YSB);  // bf16 A for xp GEMM (dead before GRU writes ys)
    u16* wihb = (u16*)(ws + OFF_WIHB); // bf16 w_ih scratch
    u16* t2b  = (u16*)(ws + OFF_XP);   // bf16 t2 (converted after fused kernel; xp dead)

    float* out = (float*)d_out;

    init_k<<<232, 256, 0, stream>>>(hidden, hb0, hsum, cnt1, cnt2, flags);
    prep_k<<<16, 256, 0, stream>>>(x, targets, hselc, list1, list2, cnt1, cnt2);

    // all fp32->bf16 weight converts in one launch
    cvt_multi_k<<<(1499648 + 255) / 256, 256, 0, stream>>>(
        w_ih, wihb, 393216,
        head_w, whb, 512512,
        t1, t1b, 512000,
        p1, pp1b, 65536,
        p2, pp2b, 16384);

    // xp = embed(x) @ w_ih^T + b_ih   [4064 x 3072] fp32, via bf16 MFMA
    emb_gather_k<<<(NR * 64 + 255) / 256, 256, 0, stream>>>(x, emb, embA);
    mfma_gemm_k<3, 0><<<dim3(32, 24), 256, 0, stream>>>(
        embA, wihb, NR, G3, ED, nullptr, nullptr, nullptr, G3,
        xp, (float*)b_ih, nullptr, nullptr, 0);

    // FUSED: GRU (64 blocks) + head/proj1/proj2 consumers (192 blocks)
    gru_fused_k<<<NBG + NCONS, 256, 0, stream>>>(
        xp, hidden, hb0, hb1, w_hh, b_hh, lengths, ysb, hT, flags,
        whb, pp1b, pp2b, p1b, p2b, hsum, hsel, hselc);

    // t2 fp32 -> bf16 once (into now-dead xp region)
    cvt_bf16_k<<<(640000 + 255) / 256, 256, 0, stream>>>(t2, t2b, 640000);

    // tail1 over compacted rows
    mfma_gemm_k<2, 0><<<dim3(32, 63), 256, 0, stream>>>(
        p1b, t1b, 0, SS1, HH1, list1, cnt1, nullptr, 0,
        t1sum, t1sel, nullptr, targets, CC0);
    // tail2 over compacted rows, B = pre-converted bf16 t2
    mfma_gemm_k<2, 0><<<dim3(32, 313), 256, 0, stream>>>(
        p2b, t2b, 0, SS2, HH2, list2, cnt2, nullptr, 0,
        t2sum, t2sel, nullptr, targets, CC1);

    finish_k<<<16, 256, 0, stream>>>(hsum, hsel, t1sum, t1sel, t2sum, t2sel,
                                     targets, losss);
    out_k<<<128, 256, 0, stream>>>(losss, hT, out);
}